// Round 3
// baseline (337.235 us; speedup 1.0000x reference)
//
#include <hip/hip_runtime.h>
#include <stdint.h>

#define A_ 128
#define S_ 512
#define D_ 768
#define MASKID 103

typedef short bf16x8_t __attribute__((ext_vector_type(8)));
typedef float floatx4_t __attribute__((ext_vector_type(4)));

__device__ __forceinline__ unsigned short f2bf(float f) {
    union { unsigned int u; float f; } v; v.f = f;
    unsigned int u = v.u;
    return (unsigned short)((u + 0x7fffu + ((u >> 16) & 1u)) >> 16);
}

// ---------------------------------------------------------------------------
// Kernel 1 (fused): blocks [0,128): full attention for one `a` —
//   online softmax per wave (rows v ≡ wave mod 8), merge in LDS,
//   write x=[att, mask_logit] (bf16 ws) and senti head -> d_out[0:256] (fp32).
// blocks [128,192): gather 50 W_prob rows (fp32 -> bf16) into ws_Wpw.
// ---------------------------------------------------------------------------
__global__ __launch_bounds__(512) void attn_fused(
    const float* __restrict__ bert,
    const int* __restrict__ ids,
    const int* __restrict__ length,
    const int* __restrict__ label_words,
    const float* __restrict__ W_prob,
    const float* __restrict__ b_prob,
    const float* __restrict__ W_senti,
    const float* __restrict__ b_senti,
    unsigned short* __restrict__ ws_Wpw,
    float* __restrict__ ws_bp,
    unsigned short* __restrict__ ws_x,
    float* __restrict__ d_out)
{
    int bx = blockIdx.x;
    int tid = threadIdx.x;
    if (bx >= A_) {                    // ---- gather branch (block-uniform)
        int r = bx - A_;               // [0, 64)
        if (r < 50) {
            int word = label_words[r];
            const float* src = W_prob + (size_t)word * D_;
            for (int j = tid; j < D_; j += 512) ws_Wpw[r * D_ + j] = f2bf(src[j]);
            if (tid == 0) ws_bp[r] = b_prob[word];
        } else {
            for (int j = tid; j < D_; j += 512) ws_Wpw[r * D_ + j] = 0;
            if (tid == 0) ws_bp[r] = 0.f;
        }
        return;
    }
    int a = bx;
    int wave = tid >> 6, lane = tid & 63;
    int d0 = lane * 12;

    __shared__ int s_minpos;
    __shared__ float red_m[8], red_l[8];
    __shared__ float red_acc[8][D_];     // 24 KB
    __shared__ float s0[8], s1[8];

    if (tid == 0) s_minpos = S_;
    __syncthreads();
    if (ids[a * S_ + tid] == MASKID) atomicMin(&s_minpos, tid);
    __syncthreads();
    int mp = (s_minpos >= S_) ? 0 : s_minpos;

    const float* base = bert + (size_t)a * S_ * D_;

    // mask_logit slice for this lane (12 floats, 3x float4)
    float ml[12];
    {
        const float4* p = (const float4*)(base + (size_t)mp * D_ + d0);
        float4 v0 = p[0], v1 = p[1], v2 = p[2];
        ml[0]=v0.x; ml[1]=v0.y; ml[2]=v0.z; ml[3]=v0.w;
        ml[4]=v1.x; ml[5]=v1.y; ml[6]=v1.z; ml[7]=v1.w;
        ml[8]=v2.x; ml[9]=v2.y; ml[10]=v2.z; ml[11]=v2.w;
    }
    int len = length[a]; if (len > S_ - 3) len = S_ - 3;

    float m = -3.0e38f, l = 0.f;
    float acc[12];
#pragma unroll
    for (int k = 0; k < 12; k++) acc[k] = 0.f;

    for (int v = wave; v < len; v += 8) {
        int s = 3 + v;
        const float4* p = (const float4*)(base + (size_t)s * D_ + d0);
        float4 v0 = p[0], v1 = p[1], v2 = p[2];
        float r[12];
        r[0]=v0.x; r[1]=v0.y; r[2]=v0.z; r[3]=v0.w;
        r[4]=v1.x; r[5]=v1.y; r[6]=v1.z; r[7]=v1.w;
        r[8]=v2.x; r[9]=v2.y; r[10]=v2.z; r[11]=v2.w;
        float part = 0.f;
#pragma unroll
        for (int k = 0; k < 12; k++) part = fmaf(r[k], ml[k], part);
#pragma unroll
        for (int off = 32; off >= 1; off >>= 1)
            part += __shfl_xor(part, off, 64);
        float mn = fmaxf(m, part);
        float alpha = __expf(m - mn);
        float wgt = __expf(part - mn);
        l = l * alpha + wgt;
#pragma unroll
        for (int k = 0; k < 12; k++) acc[k] = fmaf(acc[k], alpha, wgt * r[k]);
        m = mn;
    }
    if (lane == 0) { red_m[wave] = m; red_l[wave] = l; }
#pragma unroll
    for (int k = 0; k < 12; k++) red_acc[wave][d0 + k] = acc[k];

    // senti partials (independent of softmax merge)
    float p0 = 0.f, p1 = 0.f;
    for (int d = tid; d < D_; d += 512) {
        float b = base[d];                       // bert[a,0,d]
        p0 = fmaf(b, W_senti[d], p0);
        p1 = fmaf(b, W_senti[D_ + d], p1);
    }
#pragma unroll
    for (int off = 32; off >= 1; off >>= 1) {
        p0 += __shfl_xor(p0, off, 64);
        p1 += __shfl_xor(p1, off, 64);
    }
    if (lane == 0) { s0[wave] = p0; s1[wave] = p1; }
    __syncthreads();

    // merge 8 wave-partials (every thread redundantly; 8 expf)
    float M = red_m[0];
#pragma unroll
    for (int c = 1; c < 8; c++) M = fmaxf(M, red_m[c]);
    float fac[8]; float denom = 0.f;
#pragma unroll
    for (int c = 0; c < 8; c++) { fac[c] = __expf(red_m[c] - M); denom += fac[c] * red_l[c]; }
    float inv = 1.0f / fmaxf(denom, 1e-30f);

    const float* mrow = base + (size_t)mp * D_;
    for (int d = tid; d < D_; d += 512) {
        float s = 0.f;
#pragma unroll
        for (int c = 0; c < 8; c++) s += fac[c] * red_acc[c][d];
        ws_x[a * 1536 + d] = f2bf(s * inv);
        ws_x[a * 1536 + D_ + d] = f2bf(mrow[d]);
    }
    if (tid == 0) {
        float t0 = b_senti[0], t1 = b_senti[1];
#pragma unroll
        for (int c = 0; c < 8; c++) { t0 += s0[c]; t1 += s1[c]; }
        d_out[a * 2 + 0] = t0;
        d_out[a * 2 + 1] = t1;
    }
}

// ---------------------------------------------------------------------------
// Kernel 2: h = tanh(x @ W_dense.T + b_dense), MFMA bf16, M=128 N=768 K=1536.
// A from ws_x (bf16); B from W_dense (fp32, converted inline).
// 2-way K-split per tile; 2 tiles per block; 192 blocks.
// ---------------------------------------------------------------------------
__global__ __launch_bounds__(256) void dense_kernel(
    const unsigned short* __restrict__ ws_x,
    const float* __restrict__ W_dense,
    const float* __restrict__ b_dense,
    unsigned short* __restrict__ ws_h)
{
    int tid = threadIdx.x;
    int wave = tid >> 6, lane = tid & 63;
    int r = lane & 15, q = lane >> 4;
    int tile_local = wave >> 1, kh = wave & 1;
    int T = blockIdx.x * 2 + tile_local;   // [0, 384)
    int m_t = T / 48, n_t = T % 48;
    const bf16x8_t* Ap = (const bf16x8_t*)(ws_x + (size_t)(m_t * 16 + r) * 1536 + kh * 768 + q * 8);
    const float* Bp = W_dense + (size_t)(n_t * 16 + r) * 1536 + kh * 768 + q * 8;
    floatx4_t acc = {0.f, 0.f, 0.f, 0.f};
#pragma unroll
    for (int kk = 0; kk < 24; kk++) {
        bf16x8_t av = Ap[kk * 4];     // stride 32 bf16 = 4 x bf16x8
        float4 b0 = *(const float4*)(Bp + kk * 32);
        float4 b1 = *(const float4*)(Bp + kk * 32 + 4);
        bf16x8_t bv;
        bv[0] = (short)f2bf(b0.x); bv[1] = (short)f2bf(b0.y);
        bv[2] = (short)f2bf(b0.z); bv[3] = (short)f2bf(b0.w);
        bv[4] = (short)f2bf(b1.x); bv[5] = (short)f2bf(b1.y);
        bv[6] = (short)f2bf(b1.z); bv[7] = (short)f2bf(b1.w);
        acc = __builtin_amdgcn_mfma_f32_16x16x32_bf16(av, bv, acc, 0, 0, 0);
    }
    __shared__ float part[4][256];
#pragma unroll
    for (int reg = 0; reg < 4; reg++)
        part[wave][(q * 4 + reg) * 16 + r] = acc[reg];   // row*16+col
    __syncthreads();
    for (int t = tid; t < 512; t += 256) {
        int tl = t >> 8, id2 = t & 255;
        float sum = part[tl * 2][id2] + part[tl * 2 + 1][id2];
        int T2 = blockIdx.x * 2 + tl;
        int mt2 = T2 / 48, nt2 = T2 % 48;
        int row = id2 >> 4, col = id2 & 15;
        int n = nt2 * 16 + col;
        float h = tanhf(sum + b_dense[n]);
        ws_h[(size_t)(mt2 * 16 + row) * 768 + n] = f2bf(h);
    }
}

// ---------------------------------------------------------------------------
// Kernel 3: lp = tanh(h @ Wpw.T + bp) (M=128 N=64 K=768) + final einsum
// out[a,k,l] = sum_w lp[a, l*5+w] * W_lab[l,k,w] -> d_out[256 + ...] (fp32)
// ---------------------------------------------------------------------------
__global__ __launch_bounds__(256) void label_kernel(
    const unsigned short* __restrict__ ws_h,
    const unsigned short* __restrict__ ws_Wpw,
    const float* __restrict__ ws_bp,
    const float* __restrict__ W_lab,
    float* __restrict__ d_out)
{
    int tid = threadIdx.x;
    int wave = tid >> 6, lane = tid & 63;
    int r = lane & 15, q = lane >> 4;
    int m_t = blockIdx.x;       // 8 blocks
    int n_t = wave;             // 4 n-tiles
    const bf16x8_t* Ap = (const bf16x8_t*)(ws_h + (size_t)(m_t * 16 + r) * 768 + q * 8);
    const bf16x8_t* Bp = (const bf16x8_t*)(ws_Wpw + (size_t)(n_t * 16 + r) * 768 + q * 8);
    floatx4_t acc = {0.f, 0.f, 0.f, 0.f};
#pragma unroll
    for (int kk = 0; kk < 24; kk++)
        acc = __builtin_amdgcn_mfma_f32_16x16x32_bf16(Ap[kk * 4], Bp[kk * 4], acc, 0, 0, 0);
    __shared__ float lp_s[16][64];
    int col = n_t * 16 + r;
    float bp = ws_bp[col];
#pragma unroll
    for (int reg = 0; reg < 4; reg++)
        lp_s[q * 4 + reg][col] = tanhf(acc[reg] + bp);
    __syncthreads();
    for (int t = tid; t < 320; t += 256) {
        int al = t / 20, rem = t % 20;
        int k = rem / 10, lb = rem % 10;
        float s = 0.f;
#pragma unroll
        for (int w = 0; w < 5; w++)
            s = fmaf(lp_s[al][lb * 5 + w], W_lab[(lb * 2 + k) * 5 + w], s);
        d_out[256 + (m_t * 16 + al) * 20 + rem] = s;
    }
}

extern "C" void kernel_launch(void* const* d_in, const int* in_sizes, int n_in,
                              void* d_out, int out_size, void* d_ws, size_t ws_size,
                              hipStream_t stream) {
    const float* bert    = (const float*)d_in[0];
    const int* ids       = (const int*)d_in[1];
    const int* length    = (const int*)d_in[2];
    const int* label_words = (const int*)d_in[3];
    const float* W_senti = (const float*)d_in[4];
    const float* b_senti = (const float*)d_in[5];
    const float* W_dense = (const float*)d_in[6];
    const float* b_dense = (const float*)d_in[7];
    const float* W_prob  = (const float*)d_in[8];
    const float* b_prob  = (const float*)d_in[9];
    const float* W_lab   = (const float*)d_in[10];
    float* out = (float*)d_out;

    char* ws = (char*)d_ws;
    unsigned short* ws_x   = (unsigned short*)(ws + 0);        // 128*1536 bf16 = 393216 B
    unsigned short* ws_h   = (unsigned short*)(ws + 393216);   // 128*768  bf16 = 196608 B
    unsigned short* ws_Wpw = (unsigned short*)(ws + 589824);   // 64*768   bf16 =  98304 B
    float*          ws_bp  = (float*)(ws + 688128);            // 64 f32   =    256 B
    // total: 688384 B

    attn_fused<<<A_ + 64, 512, 0, stream>>>(bert, ids, length, label_words,
        W_prob, b_prob, W_senti, b_senti, ws_Wpw, ws_bp, ws_x, out);
    dense_kernel<<<192, 256, 0, stream>>>(ws_x, W_dense, b_dense, ws_h);
    label_kernel<<<8, 256, 0, stream>>>(ws_h, ws_Wpw, ws_bp, W_lab, out);
}

// Round 4
// 326.709 us; speedup vs baseline: 1.0322x; 1.0322x over previous
//
#include <hip/hip_runtime.h>
#include <stdint.h>

#define A_ 128
#define S_ 512
#define D_ 768
#define MASKID 103

typedef short bf16x8_t __attribute__((ext_vector_type(8)));
typedef float floatx4_t __attribute__((ext_vector_type(4)));

__device__ __forceinline__ unsigned short f2bf(float f) {
    union { unsigned int u; float f; } v; v.f = f;
    unsigned int u = v.u;
    return (unsigned short)((u + 0x7fffu + ((u >> 16) & 1u)) >> 16);
}

// ---------------------------------------------------------------------------
// Kernel 1: attention softmax partials, full-GPU.
// blocks [0,1024): a = bx>>3, chunk c = bx&7; 4 waves; rows v = c + 8*w + 32*j
//   (v ≡ c mod 8). Per-chunk online softmax -> part_m/part_l/part_acc (f32).
// blocks [1024,1088): gather 50 W_prob rows (fp32 -> bf16) into ws_Wpw.
// ---------------------------------------------------------------------------
__global__ __launch_bounds__(256) void attn_part(
    const float* __restrict__ bert,
    const int* __restrict__ ids,
    const int* __restrict__ length,
    const int* __restrict__ label_words,
    const float* __restrict__ W_prob,
    const float* __restrict__ b_prob,
    unsigned short* __restrict__ ws_Wpw,
    float* __restrict__ ws_bp,
    int* __restrict__ ws_mask_pos,
    float* __restrict__ part_m,
    float* __restrict__ part_l,
    float* __restrict__ part_acc)
{
    int bx = blockIdx.x;
    int tid = threadIdx.x;
    if (bx >= A_ * 8) {                // ---- gather branch (block-uniform)
        int r = bx - A_ * 8;           // [0, 64)
        if (r < 50) {
            int word = label_words[r];
            const float* src = W_prob + (size_t)word * D_;
            for (int j = tid; j < D_; j += 256) ws_Wpw[r * D_ + j] = f2bf(src[j]);
            if (tid == 0) ws_bp[r] = b_prob[word];
        } else {
            for (int j = tid; j < D_; j += 256) ws_Wpw[r * D_ + j] = 0;
            if (tid == 0) ws_bp[r] = 0.f;
        }
        return;
    }
    int a = bx >> 3, c = bx & 7;
    int wave = tid >> 6, lane = tid & 63;
    int d0 = lane * 12;

    __shared__ int s_minpos;
    __shared__ float red_m[4], red_l[4];
    __shared__ float red_acc[4][D_];   // 12 KB

    if (tid == 0) s_minpos = S_;
    __syncthreads();
    for (int p = tid; p < S_; p += 256)
        if (ids[a * S_ + p] == MASKID) atomicMin(&s_minpos, p);
    __syncthreads();
    int mp = (s_minpos >= S_) ? 0 : s_minpos;

    const float* base = bert + (size_t)a * S_ * D_;

    // mask_logit slice for this lane (12 floats)
    float ml[12];
    {
        const float4* p = (const float4*)(base + (size_t)mp * D_ + d0);
        float4 v0 = p[0], v1 = p[1], v2 = p[2];
        ml[0]=v0.x; ml[1]=v0.y; ml[2]=v0.z; ml[3]=v0.w;
        ml[4]=v1.x; ml[5]=v1.y; ml[6]=v1.z; ml[7]=v1.w;
        ml[8]=v2.x; ml[9]=v2.y; ml[10]=v2.z; ml[11]=v2.w;
    }
    int len = length[a]; if (len > S_ - 3) len = S_ - 3;

    float m = -3.0e38f, l = 0.f;
    float acc[12];
#pragma unroll
    for (int k = 0; k < 12; k++) acc[k] = 0.f;

    for (int v = c + 8 * wave; v < len; v += 32) {
        int s = 3 + v;
        const float4* p = (const float4*)(base + (size_t)s * D_ + d0);
        float4 v0 = p[0], v1 = p[1], v2 = p[2];
        float r[12];
        r[0]=v0.x; r[1]=v0.y; r[2]=v0.z; r[3]=v0.w;
        r[4]=v1.x; r[5]=v1.y; r[6]=v1.z; r[7]=v1.w;
        r[8]=v2.x; r[9]=v2.y; r[10]=v2.z; r[11]=v2.w;
        float part = 0.f;
#pragma unroll
        for (int k = 0; k < 12; k++) part = fmaf(r[k], ml[k], part);
#pragma unroll
        for (int off = 32; off >= 1; off >>= 1)
            part += __shfl_xor(part, off, 64);
        float mn = fmaxf(m, part);
        float alpha = __expf(m - mn);
        float wgt = __expf(part - mn);
        l = l * alpha + wgt;
#pragma unroll
        for (int k = 0; k < 12; k++) acc[k] = fmaf(acc[k], alpha, wgt * r[k]);
        m = mn;
    }
    if (lane == 0) { red_m[wave] = m; red_l[wave] = l; }
#pragma unroll
    for (int k = 0; k < 12; k++) red_acc[wave][d0 + k] = acc[k];
    __syncthreads();

    float m0 = red_m[0], m1 = red_m[1], m2 = red_m[2], m3 = red_m[3];
    float M = fmaxf(fmaxf(m0, m1), fmaxf(m2, m3));
    float f0 = __expf(m0 - M), f1 = __expf(m1 - M);
    float f2 = __expf(m2 - M), f3 = __expf(m3 - M);
    int pc = (a * 8 + c) * D_;
#pragma unroll
    for (int e = 0; e < 3; e++) {
        int d = tid + 256 * e;
        part_acc[pc + d] = f0 * red_acc[0][d] + f1 * red_acc[1][d]
                         + f2 * red_acc[2][d] + f3 * red_acc[3][d];
    }
    if (tid == 0) {
        part_m[a * 8 + c] = M;
        part_l[a * 8 + c] = f0 * red_l[0] + f1 * red_l[1] + f2 * red_l[2] + f3 * red_l[3];
        if (c == 0) ws_mask_pos[a] = mp;
    }
}

// ---------------------------------------------------------------------------
// Kernel 2: merge 8 chunk partials -> att; x=[att, mask_logit] (bf16 ws);
// senti head -> d_out[0:256] (fp32).
// ---------------------------------------------------------------------------
__global__ __launch_bounds__(256) void merge_kernel(
    const float* __restrict__ bert,
    const float* __restrict__ W_senti,
    const float* __restrict__ b_senti,
    const int* __restrict__ ws_mask_pos,
    const float* __restrict__ part_m,
    const float* __restrict__ part_l,
    const float* __restrict__ part_acc,
    unsigned short* __restrict__ ws_x,
    float* __restrict__ d_out)
{
    int a = blockIdx.x, tid = threadIdx.x;
    float mc[8], lc[8];
#pragma unroll
    for (int c = 0; c < 8; c++) { mc[c] = part_m[a * 8 + c]; lc[c] = part_l[a * 8 + c]; }
    float M = mc[0];
#pragma unroll
    for (int c = 1; c < 8; c++) M = fmaxf(M, mc[c]);
    float fac[8]; float denom = 0.f;
#pragma unroll
    for (int c = 0; c < 8; c++) { fac[c] = __expf(mc[c] - M); denom += fac[c] * lc[c]; }
    float inv = 1.0f / fmaxf(denom, 1e-30f);

    const float* pa = part_acc + (size_t)a * 8 * D_;
    int mp = ws_mask_pos[a];
    const float* mrow = bert + ((size_t)a * S_ + mp) * D_;
#pragma unroll
    for (int e = 0; e < 3; e++) {
        int d = tid + 256 * e;
        float s = 0.f;
#pragma unroll
        for (int c = 0; c < 8; c++) s += fac[c] * pa[c * D_ + d];
        ws_x[a * 1536 + d] = f2bf(s * inv);
        ws_x[a * 1536 + D_ + d] = f2bf(mrow[d]);
    }
    // senti: bert[a,0,:] @ W_senti.T + b_senti
    const float* r0 = bert + (size_t)a * S_ * D_;
    float p0 = 0.f, p1 = 0.f;
#pragma unroll
    for (int e = 0; e < 3; e++) {
        int d = tid + 256 * e;
        float b = r0[d];
        p0 = fmaf(b, W_senti[d], p0);
        p1 = fmaf(b, W_senti[D_ + d], p1);
    }
#pragma unroll
    for (int off = 32; off >= 1; off >>= 1) {
        p0 += __shfl_xor(p0, off, 64);
        p1 += __shfl_xor(p1, off, 64);
    }
    __shared__ float s0[4], s1[4];
    int wave = tid >> 6, lane = tid & 63;
    if (lane == 0) { s0[wave] = p0; s1[wave] = p1; }
    __syncthreads();
    if (tid == 0) {
        d_out[a * 2 + 0] = s0[0] + s0[1] + s0[2] + s0[3] + b_senti[0];
        d_out[a * 2 + 1] = s1[0] + s1[1] + s1[2] + s1[3] + b_senti[1];
    }
}

// ---------------------------------------------------------------------------
// Kernel 3: h = tanh(x @ W_dense.T + b_dense), MFMA bf16, M=128 N=768 K=1536.
// A from ws_x (bf16); B from W_dense (fp32, converted inline).
// ---------------------------------------------------------------------------
__global__ __launch_bounds__(256) void dense_kernel(
    const unsigned short* __restrict__ ws_x,
    const float* __restrict__ W_dense,
    const float* __restrict__ b_dense,
    unsigned short* __restrict__ ws_h)
{
    int tid = threadIdx.x;
    int wave = tid >> 6, lane = tid & 63;
    int r = lane & 15, q = lane >> 4;
    int tile_local = wave >> 1, kh = wave & 1;
    int T = blockIdx.x * 2 + tile_local;   // [0, 384)
    int m_t = T / 48, n_t = T % 48;
    const bf16x8_t* Ap = (const bf16x8_t*)(ws_x + (size_t)(m_t * 16 + r) * 1536 + kh * 768 + q * 8);
    const float* Bp = W_dense + (size_t)(n_t * 16 + r) * 1536 + kh * 768 + q * 8;
    floatx4_t acc = {0.f, 0.f, 0.f, 0.f};
#pragma unroll
    for (int kk = 0; kk < 24; kk++) {
        bf16x8_t av = Ap[kk * 4];
        float4 b0 = *(const float4*)(Bp + kk * 32);
        float4 b1 = *(const float4*)(Bp + kk * 32 + 4);
        bf16x8_t bv;
        bv[0] = (short)f2bf(b0.x); bv[1] = (short)f2bf(b0.y);
        bv[2] = (short)f2bf(b0.z); bv[3] = (short)f2bf(b0.w);
        bv[4] = (short)f2bf(b1.x); bv[5] = (short)f2bf(b1.y);
        bv[6] = (short)f2bf(b1.z); bv[7] = (short)f2bf(b1.w);
        acc = __builtin_amdgcn_mfma_f32_16x16x32_bf16(av, bv, acc, 0, 0, 0);
    }
    __shared__ float part[4][256];
#pragma unroll
    for (int reg = 0; reg < 4; reg++)
        part[wave][(q * 4 + reg) * 16 + r] = acc[reg];   // row*16+col
    __syncthreads();
    for (int t = tid; t < 512; t += 256) {
        int tl = t >> 8, id2 = t & 255;
        float sum = part[tl * 2][id2] + part[tl * 2 + 1][id2];
        int T2 = blockIdx.x * 2 + tl;
        int mt2 = T2 / 48, nt2 = T2 % 48;
        int row = id2 >> 4, col = id2 & 15;
        int n = nt2 * 16 + col;
        float h = tanhf(sum + b_dense[n]);
        ws_h[(size_t)(mt2 * 16 + row) * 768 + n] = f2bf(h);
    }
}

// ---------------------------------------------------------------------------
// Kernel 4: lp = tanh(h @ Wpw.T + bp) (M=128 N=64 K=768) + final einsum
// out[a,k,l] = sum_w lp[a, l*5+w] * W_lab[l,k,w] -> d_out[256 + ...] (fp32)
// ---------------------------------------------------------------------------
__global__ __launch_bounds__(256) void label_kernel(
    const unsigned short* __restrict__ ws_h,
    const unsigned short* __restrict__ ws_Wpw,
    const float* __restrict__ ws_bp,
    const float* __restrict__ W_lab,
    float* __restrict__ d_out)
{
    int tid = threadIdx.x;
    int wave = tid >> 6, lane = tid & 63;
    int r = lane & 15, q = lane >> 4;
    int m_t = blockIdx.x;       // 8 blocks
    int n_t = wave;             // 4 n-tiles
    const bf16x8_t* Ap = (const bf16x8_t*)(ws_h + (size_t)(m_t * 16 + r) * 768 + q * 8);
    const bf16x8_t* Bp = (const bf16x8_t*)(ws_Wpw + (size_t)(n_t * 16 + r) * 768 + q * 8);
    floatx4_t acc = {0.f, 0.f, 0.f, 0.f};
#pragma unroll
    for (int kk = 0; kk < 24; kk++)
        acc = __builtin_amdgcn_mfma_f32_16x16x32_bf16(Ap[kk * 4], Bp[kk * 4], acc, 0, 0, 0);
    __shared__ float lp_s[16][64];
    int col = n_t * 16 + r;
    float bp = ws_bp[col];
#pragma unroll
    for (int reg = 0; reg < 4; reg++)
        lp_s[q * 4 + reg][col] = tanhf(acc[reg] + bp);
    __syncthreads();
    for (int t = tid; t < 320; t += 256) {
        int al = t / 20, rem = t % 20;
        int k = rem / 10, lb = rem % 10;
        float s = 0.f;
#pragma unroll
        for (int w = 0; w < 5; w++)
            s = fmaf(lp_s[al][lb * 5 + w], W_lab[(lb * 2 + k) * 5 + w], s);
        d_out[256 + (m_t * 16 + al) * 20 + rem] = s;
    }
}

extern "C" void kernel_launch(void* const* d_in, const int* in_sizes, int n_in,
                              void* d_out, int out_size, void* d_ws, size_t ws_size,
                              hipStream_t stream) {
    const float* bert    = (const float*)d_in[0];
    const int* ids       = (const int*)d_in[1];
    const int* length    = (const int*)d_in[2];
    const int* label_words = (const int*)d_in[3];
    const float* W_senti = (const float*)d_in[4];
    const float* b_senti = (const float*)d_in[5];
    const float* W_dense = (const float*)d_in[6];
    const float* b_dense = (const float*)d_in[7];
    const float* W_prob  = (const float*)d_in[8];
    const float* b_prob  = (const float*)d_in[9];
    const float* W_lab   = (const float*)d_in[10];
    float* out = (float*)d_out;

    char* ws = (char*)d_ws;
    unsigned short* ws_x   = (unsigned short*)(ws + 0);        // 393216 B
    unsigned short* ws_h   = (unsigned short*)(ws + 393216);   // 196608 B
    unsigned short* ws_Wpw = (unsigned short*)(ws + 589824);   //  98304 B
    float*          ws_bp  = (float*)(ws + 688128);            //    256 B
    int*     ws_mask_pos   = (int*)(ws + 688384);              //    512 B
    float*          part_m = (float*)(ws + 688896);            //   4096 B
    float*          part_l = (float*)(ws + 692992);            //   4096 B
    float*        part_acc = (float*)(ws + 697088);            // 3145728 B

    attn_part<<<A_ * 8 + 64, 256, 0, stream>>>(bert, ids, length, label_words,
        W_prob, b_prob, ws_Wpw, ws_bp, ws_mask_pos, part_m, part_l, part_acc);
    merge_kernel<<<A_, 256, 0, stream>>>(bert, W_senti, b_senti, ws_mask_pos,
        part_m, part_l, part_acc, ws_x, out);
    dense_kernel<<<192, 256, 0, stream>>>(ws_x, W_dense, b_dense, ws_h);
    label_kernel<<<8, 256, 0, stream>>>(ws_h, ws_Wpw, ws_bp, W_lab, out);
}

// Round 5
// 324.966 us; speedup vs baseline: 1.0378x; 1.0054x over previous
//
#include <hip/hip_runtime.h>
#include <stdint.h>

#define A_ 128
#define S_ 512
#define D_ 768
#define MASKID 103

typedef short bf16x8_t __attribute__((ext_vector_type(8)));
typedef float floatx4_t __attribute__((ext_vector_type(4)));

__device__ __forceinline__ unsigned short f2bf(float f) {
    union { unsigned int u; float f; } v; v.f = f;
    unsigned int u = v.u;
    return (unsigned short)((u + 0x7fffu + ((u >> 16) & 1u)) >> 16);
}

// ---------------------------------------------------------------------------
// Kernel 1: attention softmax partials, full-GPU, coalesced, 2-row batched.
// blocks [0,1024): a = bx>>3, chunk c = bx&7; 4 waves; rows v = c+8w (+32 j)
// Lane d-layout: d = 4*lane + 256*j (j<3) -> every dwordx4 load is one
// contiguous 1 KB segment per wave.
// blocks [1024,1088): gather 50 W_prob rows (fp32 -> bf16) into ws_Wpw.
// ---------------------------------------------------------------------------
__global__ __launch_bounds__(256) void attn_part(
    const float* __restrict__ bert,
    const int* __restrict__ ids,
    const int* __restrict__ length,
    const int* __restrict__ label_words,
    const float* __restrict__ W_prob,
    const float* __restrict__ b_prob,
    unsigned short* __restrict__ ws_Wpw,
    float* __restrict__ ws_bp,
    int* __restrict__ ws_mask_pos,
    float* __restrict__ part_m,
    float* __restrict__ part_l,
    float* __restrict__ part_acc)
{
    int bx = blockIdx.x;
    int tid = threadIdx.x;
    if (bx >= A_ * 8) {                // ---- gather branch (block-uniform)
        int r = bx - A_ * 8;           // [0, 64)
        if (r < 50) {
            int word = label_words[r];
            const float* src = W_prob + (size_t)word * D_;
            for (int j = tid; j < D_; j += 256) ws_Wpw[r * D_ + j] = f2bf(src[j]);
            if (tid == 0) ws_bp[r] = b_prob[word];
        } else {
            for (int j = tid; j < D_; j += 256) ws_Wpw[r * D_ + j] = 0;
            if (tid == 0) ws_bp[r] = 0.f;
        }
        return;
    }
    int a = bx >> 3, c = bx & 7;
    int wave = tid >> 6, lane = tid & 63;
    int d0 = lane * 4;                 // + 256*j

    __shared__ int s_minpos;
    __shared__ float red_m[4], red_l[4];
    __shared__ float red_acc[4][D_];   // 12 KB

    if (tid == 0) s_minpos = S_;
    __syncthreads();
    for (int p = tid; p < S_; p += 256)
        if (ids[a * S_ + p] == MASKID) atomicMin(&s_minpos, p);
    __syncthreads();
    int mp = (s_minpos >= S_) ? 0 : s_minpos;

    const float* base = bert + (size_t)a * S_ * D_;

    // mask_logit slice for this lane (12 floats, coalesced layout)
    float ml[12];
    {
        const float* q = base + (size_t)mp * D_ + d0;
        float4 v0 = *(const float4*)(q);
        float4 v1 = *(const float4*)(q + 256);
        float4 v2 = *(const float4*)(q + 512);
        ml[0]=v0.x; ml[1]=v0.y; ml[2]=v0.z; ml[3]=v0.w;
        ml[4]=v1.x; ml[5]=v1.y; ml[6]=v1.z; ml[7]=v1.w;
        ml[8]=v2.x; ml[9]=v2.y; ml[10]=v2.z; ml[11]=v2.w;
    }
    int len = length[a]; if (len > S_ - 3) len = S_ - 3;

    float m = -3.0e38f, l = 0.f;
    float acc[12];
#pragma unroll
    for (int k = 0; k < 12; k++) acc[k] = 0.f;

    int v = c + 8 * wave;
    // -------- paired iterations: rows v and v+32 --------
    for (; v + 32 < len; v += 64) {
        const float* qa = base + (size_t)(3 + v) * D_ + d0;
        const float* qb = base + (size_t)(3 + v + 32) * D_ + d0;
        float4 a0 = *(const float4*)(qa);
        float4 a1 = *(const float4*)(qa + 256);
        float4 a2 = *(const float4*)(qa + 512);
        float4 b0 = *(const float4*)(qb);
        float4 b1 = *(const float4*)(qb + 256);
        float4 b2 = *(const float4*)(qb + 512);
        float ra[12], rb[12];
        ra[0]=a0.x; ra[1]=a0.y; ra[2]=a0.z; ra[3]=a0.w;
        ra[4]=a1.x; ra[5]=a1.y; ra[6]=a1.z; ra[7]=a1.w;
        ra[8]=a2.x; ra[9]=a2.y; ra[10]=a2.z; ra[11]=a2.w;
        rb[0]=b0.x; rb[1]=b0.y; rb[2]=b0.z; rb[3]=b0.w;
        rb[4]=b1.x; rb[5]=b1.y; rb[6]=b1.z; rb[7]=b1.w;
        rb[8]=b2.x; rb[9]=b2.y; rb[10]=b2.z; rb[11]=b2.w;
        float pa = 0.f, pb = 0.f;
#pragma unroll
        for (int k = 0; k < 12; k++) { pa = fmaf(ra[k], ml[k], pa); pb = fmaf(rb[k], ml[k], pb); }
#pragma unroll
        for (int off = 32; off >= 1; off >>= 1) {
            pa += __shfl_xor(pa, off, 64);
            pb += __shfl_xor(pb, off, 64);
        }
        float mn = fmaxf(m, fmaxf(pa, pb));
        float alpha = __expf(m - mn);
        float wa = __expf(pa - mn);
        float wb = __expf(pb - mn);
        l = l * alpha + wa + wb;
#pragma unroll
        for (int k = 0; k < 12; k++)
            acc[k] = fmaf(acc[k], alpha, fmaf(wa, ra[k], wb * rb[k]));
        m = mn;
    }
    // -------- single tail --------
    for (; v < len; v += 32) {
        const float* qa = base + (size_t)(3 + v) * D_ + d0;
        float4 a0 = *(const float4*)(qa);
        float4 a1 = *(const float4*)(qa + 256);
        float4 a2 = *(const float4*)(qa + 512);
        float ra[12];
        ra[0]=a0.x; ra[1]=a0.y; ra[2]=a0.z; ra[3]=a0.w;
        ra[4]=a1.x; ra[5]=a1.y; ra[6]=a1.z; ra[7]=a1.w;
        ra[8]=a2.x; ra[9]=a2.y; ra[10]=a2.z; ra[11]=a2.w;
        float pa = 0.f;
#pragma unroll
        for (int k = 0; k < 12; k++) pa = fmaf(ra[k], ml[k], pa);
#pragma unroll
        for (int off = 32; off >= 1; off >>= 1)
            pa += __shfl_xor(pa, off, 64);
        float mn = fmaxf(m, pa);
        float alpha = __expf(m - mn);
        float wa = __expf(pa - mn);
        l = l * alpha + wa;
#pragma unroll
        for (int k = 0; k < 12; k++) acc[k] = fmaf(acc[k], alpha, wa * ra[k]);
        m = mn;
    }
    if (lane == 0) { red_m[wave] = m; red_l[wave] = l; }
#pragma unroll
    for (int j = 0; j < 3; j++) {
        floatx4_t t = { acc[4*j], acc[4*j+1], acc[4*j+2], acc[4*j+3] };
        *(floatx4_t*)&red_acc[wave][d0 + 256 * j] = t;
    }
    __syncthreads();

    float m0 = red_m[0], m1 = red_m[1], m2 = red_m[2], m3 = red_m[3];
    float M = fmaxf(fmaxf(m0, m1), fmaxf(m2, m3));
    float f0 = __expf(m0 - M), f1 = __expf(m1 - M);
    float f2 = __expf(m2 - M), f3 = __expf(m3 - M);
    int pc = (a * 8 + c) * D_;
#pragma unroll
    for (int e = 0; e < 3; e++) {
        int d = tid + 256 * e;
        part_acc[pc + d] = f0 * red_acc[0][d] + f1 * red_acc[1][d]
                         + f2 * red_acc[2][d] + f3 * red_acc[3][d];
    }
    if (tid == 0) {
        part_m[a * 8 + c] = M;
        part_l[a * 8 + c] = f0 * red_l[0] + f1 * red_l[1] + f2 * red_l[2] + f3 * red_l[3];
        if (c == 0) ws_mask_pos[a] = mp;
    }
}

// ---------------------------------------------------------------------------
// Kernel 2: merge 8 chunk partials -> att; x=[att, mask_logit] (bf16 ws);
// senti head -> d_out[0:256] (fp32).
// ---------------------------------------------------------------------------
__global__ __launch_bounds__(256) void merge_kernel(
    const float* __restrict__ bert,
    const float* __restrict__ W_senti,
    const float* __restrict__ b_senti,
    const int* __restrict__ ws_mask_pos,
    const float* __restrict__ part_m,
    const float* __restrict__ part_l,
    const float* __restrict__ part_acc,
    unsigned short* __restrict__ ws_x,
    float* __restrict__ d_out)
{
    int a = blockIdx.x, tid = threadIdx.x;
    float mc[8], lc[8];
#pragma unroll
    for (int c = 0; c < 8; c++) { mc[c] = part_m[a * 8 + c]; lc[c] = part_l[a * 8 + c]; }
    float M = mc[0];
#pragma unroll
    for (int c = 1; c < 8; c++) M = fmaxf(M, mc[c]);
    float fac[8]; float denom = 0.f;
#pragma unroll
    for (int c = 0; c < 8; c++) { fac[c] = __expf(mc[c] - M); denom += fac[c] * lc[c]; }
    float inv = 1.0f / fmaxf(denom, 1e-30f);

    const float* pa = part_acc + (size_t)a * 8 * D_;
    int mp = ws_mask_pos[a];
    const float* mrow = bert + ((size_t)a * S_ + mp) * D_;
#pragma unroll
    for (int e = 0; e < 3; e++) {
        int d = tid + 256 * e;
        float s = 0.f;
#pragma unroll
        for (int c = 0; c < 8; c++) s += fac[c] * pa[c * D_ + d];
        ws_x[a * 1536 + d] = f2bf(s * inv);
        ws_x[a * 1536 + D_ + d] = f2bf(mrow[d]);
    }
    // senti: bert[a,0,:] @ W_senti.T + b_senti
    const float* r0 = bert + (size_t)a * S_ * D_;
    float p0 = 0.f, p1 = 0.f;
#pragma unroll
    for (int e = 0; e < 3; e++) {
        int d = tid + 256 * e;
        float b = r0[d];
        p0 = fmaf(b, W_senti[d], p0);
        p1 = fmaf(b, W_senti[D_ + d], p1);
    }
#pragma unroll
    for (int off = 32; off >= 1; off >>= 1) {
        p0 += __shfl_xor(p0, off, 64);
        p1 += __shfl_xor(p1, off, 64);
    }
    __shared__ float s0[4], s1[4];
    int wave = tid >> 6, lane = tid & 63;
    if (lane == 0) { s0[wave] = p0; s1[wave] = p1; }
    __syncthreads();
    if (tid == 0) {
        d_out[a * 2 + 0] = s0[0] + s0[1] + s0[2] + s0[3] + b_senti[0];
        d_out[a * 2 + 1] = s1[0] + s1[1] + s1[2] + s1[3] + b_senti[1];
    }
}

// ---------------------------------------------------------------------------
// Kernel 3: h = tanh(x @ W_dense.T + b_dense), MFMA bf16, M=128 N=768 K=1536.
// ---------------------------------------------------------------------------
__global__ __launch_bounds__(256) void dense_kernel(
    const unsigned short* __restrict__ ws_x,
    const float* __restrict__ W_dense,
    const float* __restrict__ b_dense,
    unsigned short* __restrict__ ws_h)
{
    int tid = threadIdx.x;
    int wave = tid >> 6, lane = tid & 63;
    int r = lane & 15, q = lane >> 4;
    int tile_local = wave >> 1, kh = wave & 1;
    int T = blockIdx.x * 2 + tile_local;   // [0, 384)
    int m_t = T / 48, n_t = T % 48;
    const bf16x8_t* Ap = (const bf16x8_t*)(ws_x + (size_t)(m_t * 16 + r) * 1536 + kh * 768 + q * 8);
    const float* Bp = W_dense + (size_t)(n_t * 16 + r) * 1536 + kh * 768 + q * 8;
    floatx4_t acc = {0.f, 0.f, 0.f, 0.f};
#pragma unroll
    for (int kk = 0; kk < 24; kk++) {
        bf16x8_t av = Ap[kk * 4];
        float4 b0 = *(const float4*)(Bp + kk * 32);
        float4 b1 = *(const float4*)(Bp + kk * 32 + 4);
        bf16x8_t bv;
        bv[0] = (short)f2bf(b0.x); bv[1] = (short)f2bf(b0.y);
        bv[2] = (short)f2bf(b0.z); bv[3] = (short)f2bf(b0.w);
        bv[4] = (short)f2bf(b1.x); bv[5] = (short)f2bf(b1.y);
        bv[6] = (short)f2bf(b1.z); bv[7] = (short)f2bf(b1.w);
        acc = __builtin_amdgcn_mfma_f32_16x16x32_bf16(av, bv, acc, 0, 0, 0);
    }
    __shared__ float part[4][256];
#pragma unroll
    for (int reg = 0; reg < 4; reg++)
        part[wave][(q * 4 + reg) * 16 + r] = acc[reg];   // row*16+col
    __syncthreads();
    for (int t = tid; t < 512; t += 256) {
        int tl = t >> 8, id2 = t & 255;
        float sum = part[tl * 2][id2] + part[tl * 2 + 1][id2];
        int T2 = blockIdx.x * 2 + tl;
        int mt2 = T2 / 48, nt2 = T2 % 48;
        int row = id2 >> 4, col = id2 & 15;
        int n = nt2 * 16 + col;
        float h = tanhf(sum + b_dense[n]);
        ws_h[(size_t)(mt2 * 16 + row) * 768 + n] = f2bf(h);
    }
}

// ---------------------------------------------------------------------------
// Kernel 4: lp = tanh(h @ Wpw.T + bp) (M=128 N=64 K=768) + final einsum
// ---------------------------------------------------------------------------
__global__ __launch_bounds__(256) void label_kernel(
    const unsigned short* __restrict__ ws_h,
    const unsigned short* __restrict__ ws_Wpw,
    const float* __restrict__ ws_bp,
    const float* __restrict__ W_lab,
    float* __restrict__ d_out)
{
    int tid = threadIdx.x;
    int wave = tid >> 6, lane = tid & 63;
    int r = lane & 15, q = lane >> 4;
    int m_t = blockIdx.x;       // 8 blocks
    int n_t = wave;             // 4 n-tiles
    const bf16x8_t* Ap = (const bf16x8_t*)(ws_h + (size_t)(m_t * 16 + r) * 768 + q * 8);
    const bf16x8_t* Bp = (const bf16x8_t*)(ws_Wpw + (size_t)(n_t * 16 + r) * 768 + q * 8);
    floatx4_t acc = {0.f, 0.f, 0.f, 0.f};
#pragma unroll
    for (int kk = 0; kk < 24; kk++)
        acc = __builtin_amdgcn_mfma_f32_16x16x32_bf16(Ap[kk * 4], Bp[kk * 4], acc, 0, 0, 0);
    __shared__ float lp_s[16][64];
    int col = n_t * 16 + r;
    float bp = ws_bp[col];
#pragma unroll
    for (int reg = 0; reg < 4; reg++)
        lp_s[q * 4 + reg][col] = tanhf(acc[reg] + bp);
    __syncthreads();
    for (int t = tid; t < 320; t += 256) {
        int al = t / 20, rem = t % 20;
        int k = rem / 10, lb = rem % 10;
        float s = 0.f;
#pragma unroll
        for (int w = 0; w < 5; w++)
            s = fmaf(lp_s[al][lb * 5 + w], W_lab[(lb * 2 + k) * 5 + w], s);
        d_out[256 + (m_t * 16 + al) * 20 + rem] = s;
    }
}

extern "C" void kernel_launch(void* const* d_in, const int* in_sizes, int n_in,
                              void* d_out, int out_size, void* d_ws, size_t ws_size,
                              hipStream_t stream) {
    const float* bert    = (const float*)d_in[0];
    const int* ids       = (const int*)d_in[1];
    const int* length    = (const int*)d_in[2];
    const int* label_words = (const int*)d_in[3];
    const float* W_senti = (const float*)d_in[4];
    const float* b_senti = (const float*)d_in[5];
    const float* W_dense = (const float*)d_in[6];
    const float* b_dense = (const float*)d_in[7];
    const float* W_prob  = (const float*)d_in[8];
    const float* b_prob  = (const float*)d_in[9];
    const float* W_lab   = (const float*)d_in[10];
    float* out = (float*)d_out;

    char* ws = (char*)d_ws;
    unsigned short* ws_x   = (unsigned short*)(ws + 0);        // 393216 B
    unsigned short* ws_h   = (unsigned short*)(ws + 393216);   // 196608 B
    unsigned short* ws_Wpw = (unsigned short*)(ws + 589824);   //  98304 B
    float*          ws_bp  = (float*)(ws + 688128);            //    256 B
    int*     ws_mask_pos   = (int*)(ws + 688384);              //    512 B
    float*          part_m = (float*)(ws + 688896);            //   4096 B
    float*          part_l = (float*)(ws + 692992);            //   4096 B
    float*        part_acc = (float*)(ws + 697088);            // 3145728 B

    attn_part<<<A_ * 8 + 64, 256, 0, stream>>>(bert, ids, length, label_words,
        W_prob, b_prob, ws_Wpw, ws_bp, ws_mask_pos, part_m, part_l, part_acc);
    merge_kernel<<<A_, 256, 0, stream>>>(bert, W_senti, b_senti, ws_mask_pos,
        part_m, part_l, part_acc, ws_x, out);
    dense_kernel<<<192, 256, 0, stream>>>(ws_x, W_dense, b_dense, ws_h);
    label_kernel<<<8, 256, 0, stream>>>(ws_h, ws_Wpw, ws_bp, W_lab, out);
}